// Round 1
// baseline (285.330 us; speedup 1.0000x reference)
//
#include <hip/hip_runtime.h>
#include <cstdint>
#include <cstddef>

#define M_DIM 4096
#define K_DIM 4096
#define N_DIM 11008
#define BK 64
#define NTM 32   /* M_DIM/128 */
#define NTN 86   /* N_DIM/128 */

typedef int   int4v   __attribute__((ext_vector_type(4)));
typedef float float4v __attribute__((ext_vector_type(4)));

__device__ __forceinline__ void gload_lds16(const void* g, void* l) {
  __builtin_amdgcn_global_load_lds(
      (const __attribute__((address_space(1))) unsigned int*)g,
      (__attribute__((address_space(3))) unsigned int*)l, 16, 0, 0);
}

// ---------------- x quantization: fp32 -> int8 ----------------
__global__ void quant_x_kernel(const float* __restrict__ x,
                               const float* __restrict__ scale_p,
                               const int* __restrict__ off_p,
                               signed char* __restrict__ xq, int total16) {
  const float inv = 1.0f / scale_p[0];
  const float off = (float)off_p[0];
  int tid = blockIdx.x * blockDim.x + threadIdx.x;
  int stride = gridDim.x * blockDim.x;
  const float4v* x4 = (const float4v*)x;
  int4v* out4 = (int4v*)xq;
  for (int i = tid; i < total16; i += stride) {
    int4v o;
#pragma unroll
    for (int j = 0; j < 4; ++j) {
      float4v v = x4[(size_t)i * 4 + j];
      int r = 0;
#pragma unroll
      for (int e = 0; e < 4; ++e) {
        float q = rintf(v[e] * inv) + off;     // round-half-even, matches jnp.round
        q = fminf(fmaxf(q, -128.0f), 127.0f);
        int qi = (int)q;
        r |= (qi & 0xff) << (8 * e);
      }
      o[j] = r;
    }
    out4[i] = o;
  }
}

// ---------------- weight pack: int32 carrier -> int8 ----------------
__global__ void pack_w_kernel(const int* __restrict__ w,
                              signed char* __restrict__ wq, int total16) {
  int tid = blockIdx.x * blockDim.x + threadIdx.x;
  int stride = gridDim.x * blockDim.x;
  const int4v* w4 = (const int4v*)w;
  int4v* out4 = (int4v*)wq;
  for (int i = tid; i < total16; i += stride) {
    int4v o;
#pragma unroll
    for (int j = 0; j < 4; ++j) {
      int4v v = w4[(size_t)i * 4 + j];
      o[j] = (v[0] & 0xff) | ((v[1] & 0xff) << 8) |
             ((v[2] & 0xff) << 16) | ((v[3] & 0xff) << 24);
    }
    out4[i] = o;
  }
}

// ---------------- int8 GEMM with fused dequant epilogue ----------------
// A: xq [M][K] int8, B: wq [N][K] int8 (i.e. B^T), out fp32 [M][N]
__global__ __launch_bounds__(256, 2) void gemm_i8_kernel(
    const signed char* __restrict__ A,
    const signed char* __restrict__ B,
    const int* __restrict__ qbias,
    const float* __restrict__ dscale,
    float* __restrict__ out) {
  __shared__ __attribute__((aligned(16))) signed char lA[128 * BK];  // 8 KB
  __shared__ __attribute__((aligned(16))) signed char lB[128 * BK];  // 8 KB

  const int t = threadIdx.x;
  const int lane = t & 63;
  const int wv = t >> 6;

  // XCD-aware swizzle (nwg = 2752, divisible by 8) then grouped M-supertiles
  int bid = blockIdx.x;
  const int nwg = NTM * NTN;
  const int cpx = nwg >> 3;
  int swz = (bid & 7) * cpx + (bid >> 3);
  const int GROUPM = 8;
  const int width = GROUPM * NTN;        // 688
  int group = swz / width;
  int rem = swz % width;
  int tm = group * GROUPM + (rem % GROUPM);
  int tn = rem / GROUPM;

  const signed char* Ab = A + (size_t)tm * 128 * K_DIM;
  const signed char* Bb = B + (size_t)tn * 128 * K_DIM;

  // staging source coords: each global_load_lds instr covers 256 lanes*16B = 64 rows
  const int srow = wv * 16 + (lane >> 2);   // 0..63
  const int scol = (lane & 3) * 16;

  int4v acc[4][4];
#pragma unroll
  for (int i = 0; i < 4; ++i)
#pragma unroll
    for (int j = 0; j < 4; ++j) acc[i][j] = (int4v){0, 0, 0, 0};

  const int wm = (wv >> 1) * 64;
  const int wn = (wv & 1) * 64;
  const int fr = lane & 15;
  const int klo = (lane >> 4) * 16;

  for (int kt = 0; kt < K_DIM / BK; ++kt) {
    const signed char* ga = Ab + kt * BK;
    const signed char* gb = Bb + kt * BK;
    gload_lds16(ga + (size_t)srow * K_DIM + scol,        lA + wv * 1024);
    gload_lds16(ga + (size_t)(srow + 64) * K_DIM + scol, lA + 4096 + wv * 1024);
    gload_lds16(gb + (size_t)srow * K_DIM + scol,        lB + wv * 1024);
    gload_lds16(gb + (size_t)(srow + 64) * K_DIM + scol, lB + 4096 + wv * 1024);
    __syncthreads();

    int4v afrag[4], bfrag[4];
#pragma unroll
    for (int mi = 0; mi < 4; ++mi)
      afrag[mi] = *(const int4v*)(lA + (wm + mi * 16 + fr) * BK + klo);
#pragma unroll
    for (int ni = 0; ni < 4; ++ni)
      bfrag[ni] = *(const int4v*)(lB + (wn + ni * 16 + fr) * BK + klo);

#pragma unroll
    for (int mi = 0; mi < 4; ++mi)
#pragma unroll
      for (int ni = 0; ni < 4; ++ni)
        acc[mi][ni] = __builtin_amdgcn_mfma_i32_16x16x64_i8(
            afrag[mi], bfrag[ni], acc[mi][ni], 0, 0, 0);

    __syncthreads();
  }

  // epilogue: out[m][n] = (acc + qbias[n]) * dscale[n]
  const int col = lane & 15;
  const int rb = (lane >> 4) * 4;
  const int gm0 = tm * 128 + wm;
  const int gn0 = tn * 128 + wn;
#pragma unroll
  for (int ni = 0; ni < 4; ++ni) {
    int gn = gn0 + ni * 16 + col;
    float ds = dscale[gn];
    int qb = qbias[gn];
#pragma unroll
    for (int mi = 0; mi < 4; ++mi) {
      int gm = gm0 + mi * 16 + rb;
#pragma unroll
      for (int j = 0; j < 4; ++j) {
        out[(size_t)(gm + j) * N_DIM + gn] = (float)(acc[mi][ni][j] + qb) * ds;
      }
    }
  }
}

extern "C" void kernel_launch(void* const* d_in, const int* in_sizes, int n_in,
                              void* d_out, int out_size, void* d_ws, size_t ws_size,
                              hipStream_t stream) {
  const float* x      = (const float*)d_in[0];
  const int*   w      = (const int*)d_in[1];
  const float* dscale = (const float*)d_in[2];
  const float* iscale = (const float*)d_in[3];
  const int*   ioff   = (const int*)d_in[4];
  const int*   qbias  = (const int*)d_in[5];
  float* out = (float*)d_out;

  const size_t xq_bytes = (size_t)M_DIM * K_DIM;        // 16 MB
  const size_t wq_bytes = (size_t)N_DIM * K_DIM;        // 45 MB
  if (ws_size < xq_bytes + wq_bytes) return;            // loud failure if ws too small

  signed char* xq = (signed char*)d_ws;
  signed char* wq = (signed char*)d_ws + xq_bytes;

  quant_x_kernel<<<2048, 256, 0, stream>>>(x, iscale, ioff, xq, M_DIM * K_DIM / 16);
  pack_w_kernel<<<2048, 256, 0, stream>>>(w, wq, N_DIM * K_DIM / 16);
  gemm_i8_kernel<<<NTM * NTN, 256, 0, stream>>>(xq, wq, qbias, dscale, out);
}